// Round 1
// baseline (110.116 us; speedup 1.0000x reference)
//
#include <hip/hip_runtime.h>

#define TILE 32
#define HALO 2
#define LDSD 36  // TILE + 2*HALO

__global__ __launch_bounds__(256) void fused_hsl_conv(
    const float* __restrict__ x,
    const float* __restrict__ w1,
    const float* __restrict__ b1,
    const float* __restrict__ w2,
    const float* __restrict__ b2,
    float* __restrict__ out,
    int B)
{
  constexpr int Hdim = 512, Wdim = 512;
  constexpr int tiles = Wdim / TILE; // 16
  __shared__ float sH[LDSD][LDSD];
  __shared__ float sS[LDSD][LDSD];
  __shared__ float sL[LDSD][LDSD];
  __shared__ float sw1[75];
  __shared__ float sw2[150];

  const int tid = threadIdx.x;
  if (tid < 75) sw1[tid] = w1[tid];
  else if (tid < 225) sw2[tid - 75] = w2[tid - 75];

  const int bid = blockIdx.x;
  const int tx0 = (bid % tiles) * TILE;
  const int ty0 = ((bid / tiles) % tiles) * TILE;
  const int b   = bid / (tiles * tiles);

  const size_t plane = (size_t)Hdim * Wdim;
  const float* pr = x + (size_t)b * 3 * plane;
  const float* pg = pr + plane;
  const float* pb = pg + plane;

  // Halo load + RGB->HSL fused, into LDS
  for (int i = tid; i < LDSD * LDSD; i += 256) {
    const int ly = i / LDSD, lx = i - ly * LDSD;
    const int gy = ty0 + ly - HALO, gx = tx0 + lx - HALO;
    float h = 0.f, s = 0.f, l = 0.f;
    if (gy >= 0 && gy < Hdim && gx >= 0 && gx < Wdim) {
      const size_t off = (size_t)gy * Wdim + gx;
      const float r = pr[off], g = pg[off], bl = pb[off];
      const float cmax = fmaxf(r, fmaxf(g, bl));
      const float cmin = fminf(r, fminf(g, bl));
      const float delta = cmax - cmin;
      l = 0.5f * (cmax + cmin);
      if (delta != 0.f) {
        float hv;
        if (r >= g && r >= bl) {          // argmax==0 (first max)
          hv = (g - bl) / delta;
          if (hv < 0.f) hv += 6.f;        // floor-mod into [0,6): |arg|<=1 so one add suffices
        } else if (g >= bl) {             // argmax==1
          hv = (bl - r) / delta + 2.f;
        } else {                          // argmax==2
          hv = (r - g) / delta + 4.f;
        }
        h = hv * (1.f / 6.f);
        const float denom = (l <= 0.5f) ? (2.f * l) : (2.f - 2.f * l);
        if (l > 0.f && l < 1.f) s = delta / denom;
      }
      // delta==0 -> idx=3 -> h=0; s=0 (delta/safe_den==0). Matches init.
    }
    sH[ly][lx] = h; sS[ly][lx] = s; sL[ly][lx] = l;
  }
  __syncthreads();

  const int lx = tid & 31;   // 0..31
  const int ly = tid >> 5;   // 0..7 ; each thread does rows ly, ly+8, ly+16, ly+24
  float accL[4][3], accR[4][3];
  const float bias1[3] = {b1[0], b1[1], b1[2]};
  const float bias2[3] = {b2[0], b2[1], b2[2]};
  #pragma unroll
  for (int k = 0; k < 4; ++k) {
    #pragma unroll
    for (int o = 0; o < 3; ++o) { accL[k][o] = bias1[o]; accR[k][o] = bias2[o]; }
  }

  #pragma unroll
  for (int dy = 0; dy < 5; ++dy) {
    #pragma unroll
    for (int dx = 0; dx < 5; ++dx) {
      const int wi = dy * 5 + dx;
      // w1: (O=3, I=1, 5,5); w2: (O=3, I=2, 5,5)
      const float a0 = sw1[wi], a1 = sw1[25 + wi], a2 = sw1[50 + wi];
      const float h0 = sw2[wi],      h1 = sw2[50 + wi], h2 = sw2[100 + wi];
      const float s0 = sw2[25 + wi], s1 = sw2[75 + wi], s2 = sw2[125 + wi];
      #pragma unroll
      for (int k = 0; k < 4; ++k) {
        const int yy = ly + 8 * k + dy;
        const float Lv = sL[yy][lx + dx];
        const float Hv = sH[yy][lx + dx];
        const float Sv = sS[yy][lx + dx];
        accL[k][0] = fmaf(a0, Lv, accL[k][0]);
        accL[k][1] = fmaf(a1, Lv, accL[k][1]);
        accL[k][2] = fmaf(a2, Lv, accL[k][2]);
        accR[k][0] = fmaf(h0, Hv, fmaf(s0, Sv, accR[k][0]));
        accR[k][1] = fmaf(h1, Hv, fmaf(s1, Sv, accR[k][1]));
        accR[k][2] = fmaf(h2, Hv, fmaf(s2, Sv, accR[k][2]));
      }
    }
  }

  float* outl = out + (size_t)b * 3 * plane;
  float* outr = out + (size_t)B * 3 * plane + (size_t)b * 3 * plane;
  #pragma unroll
  for (int k = 0; k < 4; ++k) {
    const size_t off = (size_t)(ty0 + ly + 8 * k) * Wdim + (tx0 + lx);
    #pragma unroll
    for (int o = 0; o < 3; ++o) {
      outl[o * plane + off] = accL[k][o];
      outr[o * plane + off] = accR[k][o];
    }
  }
}

extern "C" void kernel_launch(void* const* d_in, const int* in_sizes, int n_in,
                              void* d_out, int out_size, void* d_ws, size_t ws_size,
                              hipStream_t stream) {
  const float* x  = (const float*)d_in[0];
  const float* w1 = (const float*)d_in[1];
  const float* b1 = (const float*)d_in[2];
  const float* w2 = (const float*)d_in[3];
  const float* b2 = (const float*)d_in[4];
  float* out = (float*)d_out;

  const int B = in_sizes[0] / (3 * 512 * 512);  // 32
  const int grid = B * 16 * 16;                 // 8192 blocks
  fused_hsl_conv<<<grid, 256, 0, stream>>>(x, w1, b1, w2, b2, out, B);
}

// Round 2
// 88.449 us; speedup vs baseline: 1.2450x; 1.2450x over previous
//
#include <hip/hip_runtime.h>

#define TW 64
#define TH 32
#define LROWS 36   // TH + 4
#define LCOLS 68   // TW + 4 ; col j <-> gx = tx0 - 2 + j ; 68*4B = 272B (16B aligned stride)

__global__ __launch_bounds__(256) void fused_hsl_conv(
    const float* __restrict__ x,
    const float* __restrict__ w1,
    const float* __restrict__ b1,
    const float* __restrict__ w2,
    const float* __restrict__ b2,
    float* __restrict__ out,
    int B)
{
  constexpr int Hdim = 512, Wdim = 512;
  __shared__ float sP[3][LROWS][LCOLS];      // [H,S,L] planes
  __shared__ float swL[5][16];               // [dy][o*5+dx] repacked w1
  __shared__ float swH[5][16];               // w2 input-channel 0 (H)
  __shared__ float swS[5][16];               // w2 input-channel 1 (S)

  const int tid = threadIdx.x;

  // ---- stage + repack weights: [o][i][dy][dx] -> [dy][o*5+dx] ----
  if (tid < 75) {
    const int o = tid / 25, rem = tid % 25, dy = rem / 5, dx = rem % 5;
    swL[dy][o * 5 + dx] = w1[tid];
    swH[dy][o * 5 + dx] = w2[o * 50 + rem];
    swS[dy][o * 5 + dx] = w2[o * 50 + 25 + rem];
  }

  const int bid = blockIdx.x;
  const int tx0 = (bid & 7) * TW;
  const int ty0 = ((bid >> 3) & 15) * TH;
  const int b   = bid >> 7;

  const size_t plane = (size_t)Hdim * Wdim;
  const float* pr = x + (size_t)b * 3 * plane;
  const float* pg = pr + plane;
  const float* pb = pg + plane;

  const float b1v0 = b1[0], b1v1 = b1[1], b1v2 = b1[2];
  const float b2v0 = b2[0], b2v1 = b2[1], b2v2 = b2[2];

  // ---- halo load (float4) + RGB->HSL -> LDS ----
  // 18 aligned float4 groups per row: gx0 = tx0 - 4 + 4t, t=0..17 (always fully in or fully out of [0,512))
  for (int it = tid; it < LROWS * 18; it += 256) {
    const int row = it / 18;
    const int t   = it - row * 18;
    const int gy  = ty0 - 2 + row;
    const int gx0 = tx0 - 4 + 4 * t;
    float4 rv = {0.f,0.f,0.f,0.f}, gv = {0.f,0.f,0.f,0.f}, bv = {0.f,0.f,0.f,0.f};
    if (gy >= 0 && gy < Hdim && gx0 >= 0 && gx0 < Wdim) {
      const size_t off = (size_t)gy * Wdim + gx0;
      rv = *(const float4*)(pr + off);
      gv = *(const float4*)(pg + off);
      bv = *(const float4*)(pb + off);
    }
    const float ra[4] = {rv.x, rv.y, rv.z, rv.w};
    const float ga[4] = {gv.x, gv.y, gv.z, gv.w};
    const float ba[4] = {bv.x, bv.y, bv.z, bv.w};
    #pragma unroll
    for (int p = 0; p < 4; ++p) {
      const int j = 4 * t - 2 + p;
      const float r = ra[p], g = ga[p], bl = ba[p];
      const float cmax = fmaxf(r, fmaxf(g, bl));
      const float cmin = fminf(r, fminf(g, bl));
      const float delta = cmax - cmin;
      const float l = 0.5f * (cmax + cmin);
      const float rd = __builtin_amdgcn_rcpf(delta);     // inf/NaN path discarded by selects below
      float h0 = (g - bl) * rd;
      h0 = (h0 < 0.f) ? h0 + 6.f : h0;                   // floor-mod into [0,6)
      const float h1 = (bl - r) * rd + 2.f;
      const float h2 = (r - g) * rd + 4.f;
      float hv = (r >= g && r >= bl) ? h0 : ((g >= bl) ? h1 : h2);
      const float h = (delta != 0.f) ? hv * (1.f / 6.f) : 0.f;
      const float denom = (l <= 0.5f) ? (2.f * l) : (2.f - 2.f * l);
      const float sval = (delta != 0.f && l > 0.f && l < 1.f)
                           ? delta * __builtin_amdgcn_rcpf(denom) : 0.f;
      if (j >= 0 && j < LCOLS) {
        sP[0][row][j] = h;
        sP[1][row][j] = sval;
        sP[2][row][j] = (gy >= 0) ? l : l;  // l already 0 for out-of-range
        sP[2][row][j] = l;
      }
    }
  }
  __syncthreads();

  // ---- conv: thread = 4-wide quad x 2 adjacent rows ----
  const int lx = tid & 15;       // quad index 0..15
  const int ly = tid >> 4;       // 0..15
  const int q0 = lx * 4;         // window j = q0 .. q0+7
  const int r0 = 2 * ly;         // output rows r0, r0+1 (tile-local)

  float accA[12], accB[12];      // [o*4 + p] for rows r0 / r0+1

  // one channel pass: input plane `pl`, per-dy weight rows from `wlds`
  auto pass = [&](const float (*pl)[LCOLS], const float (*wlds)[16],
                  float* accA_, float* accB_) {
    float wbuf0[16], wbuf1[16];  // rotating per-dy weight rows (compile-time indexed)
    #pragma unroll
    for (int i = 0; i < 6; ++i) {
      // load weight row dy=i into buf[i&1]
      if (i <= 4) {
        const float4* wsrc = (const float4*)wlds[i];
        float* wdst = (i & 1) ? wbuf1 : wbuf0;
        #pragma unroll
        for (int k = 0; k < 4; ++k) {
          const float4 wv4 = wsrc[k];
          wdst[4*k+0] = wv4.x; wdst[4*k+1] = wv4.y; wdst[4*k+2] = wv4.z; wdst[4*k+3] = wv4.w;
        }
      }
      const float4 wa = *(const float4*)&pl[r0 + i][q0];
      const float4 wb = *(const float4*)&pl[r0 + i][q0 + 4];
      const float w8[8] = {wa.x, wa.y, wa.z, wa.w, wb.x, wb.y, wb.z, wb.w};
      if (i <= 4) {              // rr=0, dy=i, weights in buf[i&1]
        const float* wt = (i & 1) ? wbuf1 : wbuf0;
        #pragma unroll
        for (int dx = 0; dx < 5; ++dx)
          #pragma unroll
          for (int o = 0; o < 3; ++o) {
            const float wv = wt[o * 5 + dx];
            #pragma unroll
            for (int p = 0; p < 4; ++p)
              accA_[o * 4 + p] = fmaf(wv, w8[dx + p], accA_[o * 4 + p]);
          }
      }
      if (i >= 1) {              // rr=1, dy=i-1, weights in buf[(i-1)&1]
        const float* wt = ((i - 1) & 1) ? wbuf1 : wbuf0;
        #pragma unroll
        for (int dx = 0; dx < 5; ++dx)
          #pragma unroll
          for (int o = 0; o < 3; ++o) {
            const float wv = wt[o * 5 + dx];
            #pragma unroll
            for (int p = 0; p < 4; ++p)
              accB_[o * 4 + p] = fmaf(wv, w8[dx + p], accB_[o * 4 + p]);
          }
      }
    }
  };

  // pass 1: L -> xl
  #pragma unroll
  for (int p = 0; p < 4; ++p) {
    accA[0+p] = b1v0; accA[4+p] = b1v1; accA[8+p] = b1v2;
    accB[0+p] = b1v0; accB[4+p] = b1v1; accB[8+p] = b1v2;
  }
  pass(sP[2], swL, accA, accB);

  float* outl = out + (size_t)b * 3 * plane;
  float* outr = out + ((size_t)B + (size_t)b) * 3 * plane;
  const size_t obase = (size_t)(ty0 + r0) * Wdim + (tx0 + q0);
  #pragma unroll
  for (int o = 0; o < 3; ++o) {
    float4 v0 = {accA[o*4+0], accA[o*4+1], accA[o*4+2], accA[o*4+3]};
    float4 v1 = {accB[o*4+0], accB[o*4+1], accB[o*4+2], accB[o*4+3]};
    *(float4*)(outl + o * plane + obase)        = v0;
    *(float4*)(outl + o * plane + obase + Wdim) = v1;
  }

  // pass 2+3: H then S -> xr
  #pragma unroll
  for (int p = 0; p < 4; ++p) {
    accA[0+p] = b2v0; accA[4+p] = b2v1; accA[8+p] = b2v2;
    accB[0+p] = b2v0; accB[4+p] = b2v1; accB[8+p] = b2v2;
  }
  pass(sP[0], swH, accA, accB);
  pass(sP[1], swS, accA, accB);

  #pragma unroll
  for (int o = 0; o < 3; ++o) {
    float4 v0 = {accA[o*4+0], accA[o*4+1], accA[o*4+2], accA[o*4+3]};
    float4 v1 = {accB[o*4+0], accB[o*4+1], accB[o*4+2], accB[o*4+3]};
    *(float4*)(outr + o * plane + obase)        = v0;
    *(float4*)(outr + o * plane + obase + Wdim) = v1;
  }
}

extern "C" void kernel_launch(void* const* d_in, const int* in_sizes, int n_in,
                              void* d_out, int out_size, void* d_ws, size_t ws_size,
                              hipStream_t stream) {
  const float* x  = (const float*)d_in[0];
  const float* w1 = (const float*)d_in[1];
  const float* b1 = (const float*)d_in[2];
  const float* w2 = (const float*)d_in[3];
  const float* b2 = (const float*)d_in[4];
  float* out = (float*)d_out;

  const int B = in_sizes[0] / (3 * 512 * 512);   // 32
  const int grid = B * 8 * 16;                   // 4096 blocks (64x32 tiles)
  fused_hsl_conv<<<grid, 256, 0, stream>>>(x, w1, b1, w2, b2, out, B);
}

// Round 4
// 79.066 us; speedup vs baseline: 1.3927x; 1.1187x over previous
//
#include <hip/hip_runtime.h>

typedef _Float16 h2 __attribute__((ext_vector_type(2)));

#define TW 64
#define TH 64
#define LROWS 68
#define LCOLS 80   // padded elements per row; 160B stride (16B multiple)

__device__ __forceinline__ float fd2(unsigned a, unsigned b, float c) {
  return __builtin_amdgcn_fdot2(__builtin_bit_cast(h2, a), __builtin_bit_cast(h2, b), c, false);
}
__device__ __forceinline__ unsigned pkrtz(float a, float b) {
  return __builtin_bit_cast(unsigned, __builtin_amdgcn_cvt_pkrtz(a, b));
}

// 3 outputs x 8 px: each px needs 3 dot2 (dx pairs 01,23,4+0)
__device__ __forceinline__ void acc_row(float (&acc)[3][8], const unsigned* wt,
                                        const unsigned* w, const unsigned* s) {
  #pragma unroll
  for (int o = 0; o < 3; ++o) {
    #pragma unroll
    for (int p = 0; p < 8; ++p) {
      const int hh = p >> 1;
      const unsigned* src = (p & 1) ? s : w;  // even px: aligned pairs; odd: shifted
      acc[o][p] = fd2(src[hh],     wt[o*3+0], acc[o][p]);
      acc[o][p] = fd2(src[hh + 1], wt[o*3+1], acc[o][p]);
      acc[o][p] = fd2(src[hh + 2], wt[o*3+2], acc[o][p]);
    }
  }
}

__global__ __launch_bounds__(256, 4) void fused_hsl_conv(
    const float* __restrict__ x,
    const float* __restrict__ w1,
    const float* __restrict__ b1,
    const float* __restrict__ w2,
    const float* __restrict__ b2,
    float* __restrict__ out,
    int B)
{
  __shared__ __align__(16) _Float16 sPl[3][LROWS][LCOLS]; // 0=H,1=S,2=L (32.6 KB)
  __shared__ uint4 swq[15][3];                            // [c*5+dy][words]: 9 used of 12

  const int tid = threadIdx.x;

  // ---- pack weights into f16 dx-pairs: row c*5+dy, words o*3+{0,1,2} ----
  if (tid < 45) {
    const int o = tid % 3, dy = (tid / 3) % 5, c = tid / 15;
    float wv[5];
    #pragma unroll
    for (int dx = 0; dx < 5; ++dx)
      wv[dx] = (c == 2) ? w1[o * 25 + dy * 5 + dx]
                        : w2[o * 50 + c * 25 + dy * 5 + dx];
    unsigned* row = (unsigned*)&swq[c * 5 + dy][0];
    row[o * 3 + 0] = pkrtz(wv[0], wv[1]);
    row[o * 3 + 1] = pkrtz(wv[2], wv[3]);
    row[o * 3 + 2] = pkrtz(wv[4], 0.f);
    if (o == 0) { row[9] = 0; row[10] = 0; row[11] = 0; }
  }

  const int bid = blockIdx.x;
  const int tx0 = (bid & 7) * TW;
  const int ty0 = ((bid >> 3) & 7) * TH;
  const int b   = bid >> 6;

  const size_t pln = 512 * 512;
  const float* pr = x + (size_t)b * 3 * pln;
  const float* pg = pr + pln;
  const float* pb = pg + pln;

  // ---- halo load (aligned float4) + RGB->HSL -> f16 LDS ----
  for (int it = tid; it < LROWS * 18; it += 256) {
    const int row = it / 18;
    const int t   = it - row * 18;
    const int gy  = ty0 - 2 + row;
    const int gx0 = tx0 - 4 + 4 * t;
    float4 rv = {0.f,0.f,0.f,0.f}, gv = {0.f,0.f,0.f,0.f}, bv = {0.f,0.f,0.f,0.f};
    if (gy >= 0 && gy < 512 && gx0 >= 0 && gx0 < 512) {
      const size_t off = (size_t)gy * 512 + gx0;
      rv = *(const float4*)(pr + off);
      gv = *(const float4*)(pg + off);
      bv = *(const float4*)(pb + off);
    }
    const float ra[4] = {rv.x, rv.y, rv.z, rv.w};
    const float ga[4] = {gv.x, gv.y, gv.z, gv.w};
    const float ba[4] = {bv.x, bv.y, bv.z, bv.w};
    float hh[4], ss[4], ll[4];
    #pragma unroll
    for (int p = 0; p < 4; ++p) {
      const float r = ra[p], g = ga[p], bl = ba[p];
      const float cmax = fmaxf(r, fmaxf(g, bl));
      const float cmin = fminf(r, fminf(g, bl));
      const float delta = cmax - cmin;
      const float l = 0.5f * (cmax + cmin);
      const float rd = __builtin_amdgcn_rcpf(delta);
      float h0 = (g - bl) * rd;
      h0 = (h0 < 0.f) ? h0 + 6.f : h0;
      const float h1v = (bl - r) * rd + 2.f;
      const float h2v = (r - g) * rd + 4.f;
      float hv = (r >= g && r >= bl) ? h0 : ((g >= bl) ? h1v : h2v);
      hh[p] = (delta != 0.f) ? hv * (1.f / 6.f) : 0.f;
      const float denom = (l <= 0.5f) ? (2.f * l) : (2.f - 2.f * l);
      ss[p] = (delta != 0.f && l > 0.f && l < 1.f)
                ? delta * __builtin_amdgcn_rcpf(denom) : 0.f;
      ll[p] = l;
    }
    unsigned* rh = (unsigned*)&sPl[0][row][0];
    unsigned* rs = (unsigned*)&sPl[1][row][0];
    unsigned* rl = (unsigned*)&sPl[2][row][0];
    if (t >= 1) {            // elements 4t-2,4t-1 -> word 2t-1
      rh[2*t - 1] = pkrtz(hh[0], hh[1]);
      rs[2*t - 1] = pkrtz(ss[0], ss[1]);
      rl[2*t - 1] = pkrtz(ll[0], ll[1]);
    }
    if (t <= 16) {           // elements 4t,4t+1 -> word 2t
      rh[2*t] = pkrtz(hh[2], hh[3]);
      rs[2*t] = pkrtz(ss[2], ss[3]);
      rl[2*t] = pkrtz(ll[2], ll[3]);
    }
  }
  // zero pad region: words 34..39 (elements 68..79) of every row/plane
  for (int z = tid; z < 3 * LROWS * 6; z += 256) {
    const int p2  = z / (LROWS * 6);
    const int rem = z - p2 * (LROWS * 6);
    const int row = rem / 6;
    ((unsigned*)&sPl[p2][row][0])[34 + (rem - row * 6)] = 0;
  }
  __syncthreads();

  // ---- conv: thread = 8-wide window x 2 adjacent rows ----
  const int lx = tid & 7;        // 8 px-groups across
  const int ly = tid >> 3;       // 0..31
  const int q0 = lx * 8;         // window elements q0..q0+15 (b128 aligned: q0*2 % 16 == 0)
  const int r0 = ly * 2;

  float accA[3][8], accB[3][8];

  auto pass = [&](int c, float (&aA)[3][8], float (&aB)[3][8]) {
    unsigned wb0[9], wb1[9];
    #pragma unroll
    for (int i = 0; i < 6; ++i) {
      const unsigned* rowp = (const unsigned*)&sPl[c][r0 + i][0];
      const uint4 W0 = *(const uint4*)(rowp + (q0 >> 1));
      const uint4 W1 = *(const uint4*)(rowp + (q0 >> 1) + 4);
      const unsigned w[8] = {W0.x, W0.y, W0.z, W0.w, W1.x, W1.y, W1.z, W1.w};
      unsigned s[6];
      #pragma unroll
      for (int k = 0; k < 6; ++k)
        s[k] = __builtin_amdgcn_alignbit(w[k + 1], w[k], 16);
      if (i <= 4) {
        const uint4 a  = swq[c * 5 + i][0];
        const uint4 bq = swq[c * 5 + i][1];
        const unsigned c8 = ((const unsigned*)&swq[c * 5 + i][2])[0];
        unsigned* wd = (i & 1) ? wb1 : wb0;
        wd[0] = a.x;  wd[1] = a.y;  wd[2] = a.z;  wd[3] = a.w;
        wd[4] = bq.x; wd[5] = bq.y; wd[6] = bq.z; wd[7] = bq.w; wd[8] = c8;
        acc_row(aA, (i & 1) ? wb1 : wb0, w, s);
      }
      if (i >= 1)
        acc_row(aB, ((i - 1) & 1) ? wb1 : wb0, w, s);
    }
  };

  const float b1v[3] = {b1[0], b1[1], b1[2]};
  const float b2v[3] = {b2[0], b2[1], b2[2]};

  // pass 1: L -> xl
  #pragma unroll
  for (int o = 0; o < 3; ++o)
    #pragma unroll
    for (int p = 0; p < 8; ++p) { accA[o][p] = b1v[o]; accB[o][p] = b1v[o]; }
  pass(2, accA, accB);

  float* outl = out + (size_t)b * 3 * pln;
  float* outr = out + ((size_t)B + b) * 3 * pln;
  const size_t ob = (size_t)(ty0 + r0) * 512 + (tx0 + q0);
  #pragma unroll
  for (int o = 0; o < 3; ++o) {
    *(float4*)(outl + o * pln + ob)       = make_float4(accA[o][0], accA[o][1], accA[o][2], accA[o][3]);
    *(float4*)(outl + o * pln + ob + 4)   = make_float4(accA[o][4], accA[o][5], accA[o][6], accA[o][7]);
    *(float4*)(outl + o * pln + ob + 512) = make_float4(accB[o][0], accB[o][1], accB[o][2], accB[o][3]);
    *(float4*)(outl + o * pln + ob + 516) = make_float4(accB[o][4], accB[o][5], accB[o][6], accB[o][7]);
  }

  // pass 2+3: H then S -> xr
  #pragma unroll
  for (int o = 0; o < 3; ++o)
    #pragma unroll
    for (int p = 0; p < 8; ++p) { accA[o][p] = b2v[o]; accB[o][p] = b2v[o]; }
  pass(0, accA, accB);
  pass(1, accA, accB);

  #pragma unroll
  for (int o = 0; o < 3; ++o) {
    *(float4*)(outr + o * pln + ob)       = make_float4(accA[o][0], accA[o][1], accA[o][2], accA[o][3]);
    *(float4*)(outr + o * pln + ob + 4)   = make_float4(accA[o][4], accA[o][5], accA[o][6], accA[o][7]);
    *(float4*)(outr + o * pln + ob + 512) = make_float4(accB[o][0], accB[o][1], accB[o][2], accB[o][3]);
    *(float4*)(outr + o * pln + ob + 516) = make_float4(accB[o][4], accB[o][5], accB[o][6], accB[o][7]);
  }
}

extern "C" void kernel_launch(void* const* d_in, const int* in_sizes, int n_in,
                              void* d_out, int out_size, void* d_ws, size_t ws_size,
                              hipStream_t stream) {
  const float* x  = (const float*)d_in[0];
  const float* w1 = (const float*)d_in[1];
  const float* b1 = (const float*)d_in[2];
  const float* w2 = (const float*)d_in[3];
  const float* b2 = (const float*)d_in[4];
  float* out = (float*)d_out;

  const int B = in_sizes[0] / (3 * 512 * 512);   // 32
  const int grid = B * 8 * 8;                    // 2048 blocks (64x64 tiles)
  fused_hsl_conv<<<grid, 256, 0, stream>>>(x, w1, b1, w2, b2, out, B);
}

// Round 5
// 76.804 us; speedup vs baseline: 1.4337x; 1.0294x over previous
//
#include <hip/hip_runtime.h>

typedef _Float16 h2 __attribute__((ext_vector_type(2)));

__device__ __forceinline__ float fd2(unsigned a, unsigned b, float c) {
  return __builtin_amdgcn_fdot2(__builtin_bit_cast(h2, a), __builtin_bit_cast(h2, b), c, false);
}
__device__ __forceinline__ unsigned pkrtz(float a, float b) {
  return __builtin_bit_cast(unsigned, __builtin_amdgcn_cvt_pkrtz(a, b));
}

#define TW 64
#define TH 32
#define ROWS 36   // TH + 4
#define SWW 84    // sHS row stride (words);  84*4=336B = 21*16  ✓ aligned, shift 20 mod 32
#define SLW 88    // sL  row stride (f16s);   88*2=176B = 11*16  ✓ aligned, shift 12 mod 32

// LDS col c = gx - tx0 + 2, c in [0,68). Output px X needs cols X..X+4.
__global__ __launch_bounds__(256, 6) void fused_hsl_conv(
    const float* __restrict__ x,
    const float* __restrict__ w1,
    const float* __restrict__ b1,
    const float* __restrict__ w2,
    const float* __restrict__ b2,
    float* __restrict__ out,
    int B)
{
  __shared__ unsigned sHS[ROWS][SWW];              // (H,S) f16 pair per px
  __shared__ __align__(16) _Float16 sL[ROWS][SLW]; // L plane
  __shared__ unsigned swHS[5][16];                 // [dy][o*5+dx] = (wH,wS) pairs
  __shared__ unsigned swL[5][16];                  // [dy][o*3+k]  = dx-pair packed w1

  const int tid = threadIdx.x;

  // ---- weight staging ----
  if (tid < 15) {                       // HS weights: (o,dy)
    const int o = tid % 3, dy = tid / 3;
    #pragma unroll
    for (int dx = 0; dx < 5; ++dx)
      swHS[dy][o * 5 + dx] = pkrtz(w2[o * 50 + dy * 5 + dx],
                                   w2[o * 50 + 25 + dy * 5 + dx]);
  } else if (tid >= 32 && tid < 47) {   // L weights
    const int t2 = tid - 32, o = t2 % 3, dy = t2 / 3;
    float wv[5];
    #pragma unroll
    for (int dx = 0; dx < 5; ++dx) wv[dx] = w1[o * 25 + dy * 5 + dx];
    swL[dy][o * 3 + 0] = pkrtz(wv[0], wv[1]);
    swL[dy][o * 3 + 1] = pkrtz(wv[2], wv[3]);
    swL[dy][o * 3 + 2] = pkrtz(wv[4], 0.f);
  } else if (tid >= 64 && tid < 69) {   // pad words
    swHS[tid - 64][15] = 0;
  } else if (tid >= 96 && tid < 131) {
    const int t3 = tid - 96;
    swL[t3 / 7][9 + t3 % 7] = 0;
  }

  // ---- tile decomposition with bijective XCD swizzle (y-adjacent contiguous) ----
  const int nwg = gridDim.x;                       // B*128, %8==0
  const int bsw = (blockIdx.x & 7) * (nwg >> 3) + (blockIdx.x >> 3);
  const int ty0 = (bsw & 15) * TH;
  const int tx0 = ((bsw >> 4) & 7) * TW;
  const int b   = bsw >> 7;

  const size_t pln = 512 * 512;
  const float* pr = x + (size_t)b * 3 * pln;
  const float* pg = pr + pln;
  const float* pb = pg + pln;

  // ---- halo staging: 36 rows x 18 float4-groups = 648 items; threads 0..215 x 3 ----
  float4 Rv[3], Gv[3], Bv[3];
  int rowA[3], tA[3];
  const bool act = tid < 216;
  #pragma unroll
  for (int k = 0; k < 3; ++k) {
    const int i = k * 216 + tid;
    const int row = i / 18, t = i - row * 18;
    rowA[k] = row; tA[k] = t;
    const int gy = ty0 - 2 + row;
    const int gx0 = tx0 - 4 + 4 * t;
    Rv[k] = make_float4(0.f, 0.f, 0.f, 0.f);
    Gv[k] = Rv[k]; Bv[k] = Rv[k];
    if (act && gy >= 0 && gy < 512 && gx0 >= 0 && gx0 < 512) {
      const size_t off = (size_t)gy * 512 + gx0;
      Rv[k] = *(const float4*)(pr + off);
      Gv[k] = *(const float4*)(pg + off);
      Bv[k] = *(const float4*)(pb + off);
    }
  }
  #pragma unroll
  for (int k = 0; k < 3; ++k) {
    const int row = rowA[k], t = tA[k];
    const float ra[4] = {Rv[k].x, Rv[k].y, Rv[k].z, Rv[k].w};
    const float ga[4] = {Gv[k].x, Gv[k].y, Gv[k].z, Gv[k].w};
    const float ba[4] = {Bv[k].x, Bv[k].y, Bv[k].z, Bv[k].w};
    unsigned hs[4]; _Float16 lv[4];
    #pragma unroll
    for (int p = 0; p < 4; ++p) {
      const float r = ra[p], g = ga[p], bl = ba[p];
      const float cmax = fmaxf(r, fmaxf(g, bl));
      const float cmin = fminf(r, fminf(g, bl));
      const float delta = cmax - cmin;
      const float l = 0.5f * (cmax + cmin);
      const float rd = __builtin_amdgcn_rcpf(delta);
      float h0 = (g - bl) * rd;
      h0 = (h0 < 0.f) ? h0 + 6.f : h0;
      const float h1v = (bl - r) * rd + 2.f;
      const float h2v = (r - g) * rd + 4.f;
      float hv = (r >= g && r >= bl) ? h0 : ((g >= bl) ? h1v : h2v);
      const float h = (delta != 0.f) ? hv * (1.f / 6.f) : 0.f;
      const float denom = (l <= 0.5f) ? (2.f * l) : (2.f - 2.f * l);
      const float s = (delta != 0.f && l > 0.f && l < 1.f)
                        ? delta * __builtin_amdgcn_rcpf(denom) : 0.f;
      hs[p] = pkrtz(h, s);
      lv[p] = (_Float16)l;
    }
    if (act) {
      // HS: px p -> col 4t-2+p -> word (4t-2+p)
      if (t >= 1)  *(uint2*)&sHS[row][4 * t - 2] = make_uint2(hs[0], hs[1]);
      if (t <= 16) *(uint2*)&sHS[row][4 * t]     = make_uint2(hs[2], hs[3]);
      // L: f16 pairs -> word (col/2)
      unsigned* rl = (unsigned*)&sL[row][0];
      if (t >= 1)  rl[2 * t - 1] = __builtin_bit_cast(unsigned, (h2){lv[0], lv[1]});
      if (t <= 16) rl[2 * t]     = __builtin_bit_cast(unsigned, (h2){lv[2], lv[3]});
    }
  }
  // zero L pad cols 68..71 (words 34,35) — read by lx=7's second b128
  if (tid < 72) ((unsigned*)&sL[tid >> 1][0])[34 + (tid & 1)] = 0;
  __syncthreads();

  // ---- conv: thread = one output row (ly) x 8 px (q0..q0+7) ----
  const int lx = tid & 7;
  const int ly = tid >> 3;      // 0..31
  const int q0 = 8 * lx;

  float* outl = out + (size_t)b * 3 * pln;
  float* outr = out + ((size_t)B + b) * 3 * pln;
  const size_t ob = (size_t)(ty0 + ly) * 512 + (tx0 + q0);

  // pass 1: HS -> xr  (tap dx for px p uses word q0+p+dx)
  {
    float acc[3][8];
    const float b2v[3] = {b2[0], b2[1], b2[2]};
    #pragma unroll
    for (int o = 0; o < 3; ++o)
      #pragma unroll
      for (int p = 0; p < 8; ++p) acc[o][p] = b2v[o];

    #pragma unroll
    for (int dy = 0; dy < 5; ++dy) {
      const unsigned* rowp = &sHS[ly + dy][0];
      const uint4 A0 = *(const uint4*)(rowp + q0);
      const uint4 A1 = *(const uint4*)(rowp + q0 + 4);
      const uint4 A2 = *(const uint4*)(rowp + q0 + 8);
      const unsigned hw[12] = {A0.x, A0.y, A0.z, A0.w, A1.x, A1.y, A1.z, A1.w,
                               A2.x, A2.y, A2.z, A2.w};
      const uint4 W0 = *(const uint4*)&swHS[dy][0];
      const uint4 W1 = *(const uint4*)&swHS[dy][4];
      const uint4 W2 = *(const uint4*)&swHS[dy][8];
      const uint4 W3 = *(const uint4*)&swHS[dy][12];
      const unsigned wt[15] = {W0.x, W0.y, W0.z, W0.w, W1.x, W1.y, W1.z, W1.w,
                               W2.x, W2.y, W2.z, W2.w, W3.x, W3.y, W3.z};
      #pragma unroll
      for (int o = 0; o < 3; ++o)
        #pragma unroll
        for (int p = 0; p < 8; ++p)
          #pragma unroll
          for (int dx = 0; dx < 5; ++dx)
            acc[o][p] = fd2(hw[p + dx], wt[o * 5 + dx], acc[o][p]);
    }
    #pragma unroll
    for (int o = 0; o < 3; ++o) {
      *(float4*)(outr + o * pln + ob)     = make_float4(acc[o][0], acc[o][1], acc[o][2], acc[o][3]);
      *(float4*)(outr + o * pln + ob + 4) = make_float4(acc[o][4], acc[o][5], acc[o][6], acc[o][7]);
    }
  }

  // pass 2: L -> xl  (dx-pair packed, alignbit for odd px)
  {
    float acc[3][8];
    const float b1v[3] = {b1[0], b1[1], b1[2]};
    #pragma unroll
    for (int o = 0; o < 3; ++o)
      #pragma unroll
      for (int p = 0; p < 8; ++p) acc[o][p] = b1v[o];

    #pragma unroll
    for (int dy = 0; dy < 5; ++dy) {
      const unsigned* rowp = (const unsigned*)&sL[ly + dy][0];
      const uint4 L0 = *(const uint4*)(rowp + 4 * lx);
      const uint4 L1 = *(const uint4*)(rowp + 4 * lx + 4);
      const unsigned w[8] = {L0.x, L0.y, L0.z, L0.w, L1.x, L1.y, L1.z, L1.w};
      unsigned s[6];
      #pragma unroll
      for (int k = 0; k < 6; ++k)
        s[k] = __builtin_amdgcn_alignbit(w[k + 1], w[k], 16);
      const uint4 V0 = *(const uint4*)&swL[dy][0];
      const uint4 V1 = *(const uint4*)&swL[dy][4];
      const unsigned c8 = swL[dy][8];
      const unsigned wt[9] = {V0.x, V0.y, V0.z, V0.w, V1.x, V1.y, V1.z, V1.w, c8};
      #pragma unroll
      for (int o = 0; o < 3; ++o)
        #pragma unroll
        for (int p = 0; p < 8; ++p) {
          const int hh = p >> 1;
          const unsigned* src = (p & 1) ? s : w;
          acc[o][p] = fd2(src[hh],     wt[o * 3 + 0], acc[o][p]);
          acc[o][p] = fd2(src[hh + 1], wt[o * 3 + 1], acc[o][p]);
          acc[o][p] = fd2(src[hh + 2], wt[o * 3 + 2], acc[o][p]);
        }
    }
    #pragma unroll
    for (int o = 0; o < 3; ++o) {
      *(float4*)(outl + o * pln + ob)     = make_float4(acc[o][0], acc[o][1], acc[o][2], acc[o][3]);
      *(float4*)(outl + o * pln + ob + 4) = make_float4(acc[o][4], acc[o][5], acc[o][6], acc[o][7]);
    }
  }
}

extern "C" void kernel_launch(void* const* d_in, const int* in_sizes, int n_in,
                              void* d_out, int out_size, void* d_ws, size_t ws_size,
                              hipStream_t stream) {
  const float* x  = (const float*)d_in[0];
  const float* w1 = (const float*)d_in[1];
  const float* b1 = (const float*)d_in[2];
  const float* w2 = (const float*)d_in[3];
  const float* b2 = (const float*)d_in[4];
  float* out = (float*)d_out;

  const int B = in_sizes[0] / (3 * 512 * 512);   // 32
  const int grid = B * 8 * 16;                   // 4096 blocks (64x32 tiles)
  fused_hsl_conv<<<grid, 256, 0, stream>>>(x, w1, b1, w2, b2, out, B);
}

// Round 7
// 73.407 us; speedup vs baseline: 1.5001x; 1.0463x over previous
//
#include <hip/hip_runtime.h>

typedef _Float16 h2 __attribute__((ext_vector_type(2)));

__device__ __forceinline__ float fd2(unsigned a, unsigned b, float c) {
  return __builtin_amdgcn_fdot2(__builtin_bit_cast(h2, a), __builtin_bit_cast(h2, b), c, false);
}
__device__ __forceinline__ unsigned pkrtz(float a, float b) {
  return __builtin_bit_cast(unsigned, __builtin_amdgcn_cvt_pkrtz(a, b));
}

#define TW 64
#define TH 32
#define ROWS 36   // TH + 4
#define SWW 84    // sHS row stride (words);  336B = 21*16  aligned, shift 20 mod 32
#define SLW 88    // sL  row stride (f16s);   176B = 11*16  aligned, shift 12 mod 32
#define NT 4      // tiles (stacked in y) per block

__global__ __launch_bounds__(256, 4) void fused_hsl_conv(
    const float* __restrict__ x,
    const float* __restrict__ w1,
    const float* __restrict__ b1,
    const float* __restrict__ w2,
    const float* __restrict__ b2,
    float* __restrict__ out,
    int B)
{
  __shared__ unsigned sHS[2][ROWS][SWW];              // (H,S) f16 pair per px
  __shared__ __align__(16) _Float16 sL[2][ROWS][SLW]; // L plane
  __shared__ unsigned swHS[5][16];                    // [dy][o*5+dx] = (wH,wS)
  __shared__ unsigned swL[5][16];                     // [dy][o*3+k]  dx-pair w1

  const int tid = threadIdx.x;

  // ---- weight staging ----
  if (tid < 15) {
    const int o = tid % 3, dy = tid / 3;
    #pragma unroll
    for (int dx = 0; dx < 5; ++dx)
      swHS[dy][o * 5 + dx] = pkrtz(w2[o * 50 + dy * 5 + dx],
                                   w2[o * 50 + 25 + dy * 5 + dx]);
  } else if (tid >= 32 && tid < 47) {
    const int t2 = tid - 32, o = t2 % 3, dy = t2 / 3;
    float wv[5];
    #pragma unroll
    for (int dx = 0; dx < 5; ++dx) wv[dx] = w1[o * 25 + dy * 5 + dx];
    swL[dy][o * 3 + 0] = pkrtz(wv[0], wv[1]);
    swL[dy][o * 3 + 1] = pkrtz(wv[2], wv[3]);
    swL[dy][o * 3 + 2] = pkrtz(wv[4], 0.f);
  } else if (tid >= 64 && tid < 69) {
    swHS[tid - 64][15] = 0;
  } else if (tid >= 96 && tid < 131) {
    const int t3 = tid - 96;
    swL[t3 / 7][9 + t3 % 7] = 0;
  }
  // zero sL pad words 34,35 (cols 68..71) of every row, BOTH buffers (144 words)
  if (tid < 72) {
    const int r = tid >> 1, w = 34 + (tid & 1);
    ((unsigned*)&sL[0][r][0])[w] = 0;
    ((unsigned*)&sL[1][r][0])[w] = 0;
  }

  // ---- block -> (b, tx, ychunk) with bijective XCD swizzle ----
  const int nwg = gridDim.x;                      // B*32, %8==0
  const int bsw = (blockIdx.x & 7) * (nwg >> 3) + (blockIdx.x >> 3);
  const int b   = bsw >> 5;
  const int rem = bsw & 31;
  const int tx0 = (rem & 7) * TW;
  const int tyb = (rem >> 3) * (NT * TH);         // 0,128,256,384

  const size_t pln = 512 * 512;
  const float* pr = x + (size_t)b * 3 * pln;
  const float* pg = pr + pln;
  const float* pb = pg + pln;
  float* outl = out + (size_t)b * 3 * pln;
  float* outr = out + ((size_t)B + b) * 3 * pln;

  const float b1v0 = b1[0], b1v1 = b1[1], b1v2 = b1[2];
  const float b2v0 = b2[0], b2v1 = b2[1], b2v2 = b2[2];

  // staging geometry: 36 rows x 18 float4-groups = 648 = 3*216
  const bool act = tid < 216;
  int rowA[3], tA[3];
  #pragma unroll
  for (int k = 0; k < 3; ++k) {
    const int i = k * 216 + tid;
    rowA[k] = i / 18;
    tA[k]   = i - rowA[k] * 18;
  }

  auto issue_loads = [&](int ty0, float4* Rv, float4* Gv, float4* Bv) {
    #pragma unroll
    for (int k = 0; k < 3; ++k) {
      const int gy  = ty0 - 2 + rowA[k];
      const int gx0 = tx0 - 4 + 4 * tA[k];
      Rv[k] = make_float4(0.f, 0.f, 0.f, 0.f);
      Gv[k] = Rv[k]; Bv[k] = Rv[k];
      if (act && gy >= 0 && gy < 512 && gx0 >= 0 && gx0 < 512) {
        const size_t off = (size_t)gy * 512 + gx0;
        Rv[k] = *(const float4*)(pr + off);
        Gv[k] = *(const float4*)(pg + off);
        Bv[k] = *(const float4*)(pb + off);
      }
    }
  };

  auto convert_store = [&](int buf, const float4* Rv, const float4* Gv, const float4* Bv) {
    #pragma unroll
    for (int k = 0; k < 3; ++k) {
      const int row = rowA[k], t = tA[k];
      const float ra[4] = {Rv[k].x, Rv[k].y, Rv[k].z, Rv[k].w};
      const float ga[4] = {Gv[k].x, Gv[k].y, Gv[k].z, Gv[k].w};
      const float ba[4] = {Bv[k].x, Bv[k].y, Bv[k].z, Bv[k].w};
      unsigned hs[4]; _Float16 lv[4];
      #pragma unroll
      for (int p = 0; p < 4; ++p) {
        const float r = ra[p], g = ga[p], bl = ba[p];
        const float cmax = fmaxf(r, fmaxf(g, bl));
        const float cmin = fminf(r, fminf(g, bl));
        const float delta = cmax - cmin;
        const float l = 0.5f * (cmax + cmin);
        const float rd = __builtin_amdgcn_rcpf(delta);
        float h0 = (g - bl) * rd;
        h0 = (h0 < 0.f) ? h0 + 6.f : h0;
        const float h1v = (bl - r) * rd + 2.f;
        const float h2v = (r - g) * rd + 4.f;
        float hv = (r >= g && r >= bl) ? h0 : ((g >= bl) ? h1v : h2v);
        const float h = (delta != 0.f) ? hv * (1.f / 6.f) : 0.f;
        const float denom = (l <= 0.5f) ? (2.f * l) : (2.f - 2.f * l);
        const float s = (delta != 0.f && l > 0.f && l < 1.f)
                          ? delta * __builtin_amdgcn_rcpf(denom) : 0.f;
        hs[p] = pkrtz(h, s);
        lv[p] = (_Float16)l;
      }
      if (act) {
        if (t >= 1)  *(uint2*)&sHS[buf][row][4 * t - 2] = make_uint2(hs[0], hs[1]);
        if (t <= 16) *(uint2*)&sHS[buf][row][4 * t]     = make_uint2(hs[2], hs[3]);
        unsigned* rl = (unsigned*)&sL[buf][row][0];
        if (t >= 1)  rl[2 * t - 1] = __builtin_bit_cast(unsigned, (h2){lv[0], lv[1]});
        if (t <= 16) rl[2 * t]     = __builtin_bit_cast(unsigned, (h2){lv[2], lv[3]});
      }
    }
  };

  const int lx = tid & 7;
  const int ly = tid >> 3;      // 0..31
  const int q0 = 8 * lx;

  // ---- prologue: tile 0 ----
  float4 Rv[3], Gv[3], Bv[3];
  issue_loads(tyb, Rv, Gv, Bv);
  convert_store(0, Rv, Gv, Bv);
  __syncthreads();

  for (int it = 0; it < NT; ++it) {
    const int ty0 = tyb + it * TH;
    const int buf = it & 1;

    // issue next tile's loads (stay in flight under compute)
    float4 Rn[3], Gn[3], Bn[3];
    if (it + 1 < NT) issue_loads(ty0 + TH, Rn, Gn, Bn);

    const size_t ob = (size_t)(ty0 + ly) * 512 + (tx0 + q0);

    // pass 1: HS -> xr
    {
      float acc[3][8];
      #pragma unroll
      for (int p = 0; p < 8; ++p) { acc[0][p] = b2v0; acc[1][p] = b2v1; acc[2][p] = b2v2; }
      #pragma unroll
      for (int dy = 0; dy < 5; ++dy) {
        const unsigned* rowp = &sHS[buf][ly + dy][0];
        const uint4 A0 = *(const uint4*)(rowp + q0);
        const uint4 A1 = *(const uint4*)(rowp + q0 + 4);
        const uint4 A2 = *(const uint4*)(rowp + q0 + 8);
        const unsigned hw[12] = {A0.x, A0.y, A0.z, A0.w, A1.x, A1.y, A1.z, A1.w,
                                 A2.x, A2.y, A2.z, A2.w};
        const uint4 W0 = *(const uint4*)&swHS[dy][0];
        const uint4 W1 = *(const uint4*)&swHS[dy][4];
        const uint4 W2 = *(const uint4*)&swHS[dy][8];
        const uint4 W3 = *(const uint4*)&swHS[dy][12];
        const unsigned wt[15] = {W0.x, W0.y, W0.z, W0.w, W1.x, W1.y, W1.z, W1.w,
                                 W2.x, W2.y, W2.z, W2.w, W3.x, W3.y, W3.z};
        #pragma unroll
        for (int o = 0; o < 3; ++o)
          #pragma unroll
          for (int p = 0; p < 8; ++p)
            #pragma unroll
            for (int dx = 0; dx < 5; ++dx)
              acc[o][p] = fd2(hw[p + dx], wt[o * 5 + dx], acc[o][p]);
      }
      #pragma unroll
      for (int o = 0; o < 3; ++o) {
        *(float4*)(outr + o * pln + ob)     = make_float4(acc[o][0], acc[o][1], acc[o][2], acc[o][3]);
        *(float4*)(outr + o * pln + ob + 4) = make_float4(acc[o][4], acc[o][5], acc[o][6], acc[o][7]);
      }
    }

    // pass 2: L -> xl
    {
      float acc[3][8];
      #pragma unroll
      for (int p = 0; p < 8; ++p) { acc[0][p] = b1v0; acc[1][p] = b1v1; acc[2][p] = b1v2; }
      #pragma unroll
      for (int dy = 0; dy < 5; ++dy) {
        const unsigned* rowp = (const unsigned*)&sL[buf][ly + dy][0];
        const uint4 L0 = *(const uint4*)(rowp + 4 * lx);
        const uint4 L1 = *(const uint4*)(rowp + 4 * lx + 4);
        const unsigned w[8] = {L0.x, L0.y, L0.z, L0.w, L1.x, L1.y, L1.z, L1.w};
        unsigned s[6];
        #pragma unroll
        for (int k = 0; k < 6; ++k)
          s[k] = __builtin_amdgcn_alignbit(w[k + 1], w[k], 16);
        const uint4 V0 = *(const uint4*)&swL[dy][0];
        const uint4 V1 = *(const uint4*)&swL[dy][4];
        const unsigned c8 = swL[dy][8];
        const unsigned wt[9] = {V0.x, V0.y, V0.z, V0.w, V1.x, V1.y, V1.z, V1.w, c8};
        #pragma unroll
        for (int o = 0; o < 3; ++o)
          #pragma unroll
          for (int p = 0; p < 8; ++p) {
            const int hh = p >> 1;
            const unsigned* src = (p & 1) ? s : w;
            acc[o][p] = fd2(src[hh],     wt[o * 3 + 0], acc[o][p]);
            acc[o][p] = fd2(src[hh + 1], wt[o * 3 + 1], acc[o][p]);
            acc[o][p] = fd2(src[hh + 2], wt[o * 3 + 2], acc[o][p]);
          }
      }
      #pragma unroll
      for (int o = 0; o < 3; ++o) {
        *(float4*)(outl + o * pln + ob)     = make_float4(acc[o][0], acc[o][1], acc[o][2], acc[o][3]);
        *(float4*)(outl + o * pln + ob + 4) = make_float4(acc[o][4], acc[o][5], acc[o][6], acc[o][7]);
      }
    }

    // stage next tile into the other buffer (waits on the in-flight loads here)
    if (it + 1 < NT) convert_store(buf ^ 1, Rn, Gn, Bn);
    __syncthreads();
  }
}

extern "C" void kernel_launch(void* const* d_in, const int* in_sizes, int n_in,
                              void* d_out, int out_size, void* d_ws, size_t ws_size,
                              hipStream_t stream) {
  const float* x  = (const float*)d_in[0];
  const float* w1 = (const float*)d_in[1];
  const float* b1 = (const float*)d_in[2];
  const float* w2 = (const float*)d_in[3];
  const float* b2 = (const float*)d_in[4];
  float* out = (float*)d_out;

  const int B = in_sizes[0] / (3 * 512 * 512);   // 32
  const int grid = B * 32;                       // 1024 persistent-ish blocks, 4 tiles each
  fused_hsl_conv<<<grid, 256, 0, stream>>>(x, w1, b1, w2, b2, out, B);
}